// Round 10
// baseline (342.839 us; speedup 1.0000x reference)
//
#include <hip/hip_runtime.h>

// ---------- types ----------
typedef unsigned short bf16_t;                                    // raw bf16 bits
typedef __bf16 bf16x8 __attribute__((ext_vector_type(8)));        // MFMA A/B frag (4 VGPRs)
typedef float  v4f   __attribute__((ext_vector_type(4)));         // 16x16 MFMA C/D frag
typedef float  v16f  __attribute__((ext_vector_type(16)));        // 32x32 MFMA C/D frag
typedef unsigned u32x2 __attribute__((ext_vector_type(2)));

// round-to-nearest-even f32 -> bf16 (branchless; inputs are finite)
__device__ __forceinline__ bf16_t f2bf(float f) {
    union { float f; unsigned u; } a; a.f = f;
    unsigned r = a.u + 0x7FFFu + ((a.u >> 16) & 1u);
    return (bf16_t)(r >> 16);
}

// pack two f32 -> bf16x2 dword (hardware RNE): low16 = bf16(lo), high16 = bf16(hi)
__device__ __forceinline__ unsigned cvtpk(float lo, float hi) {
    unsigned r;
    asm("v_cvt_pk_bf16_f32 %0, %1, %2" : "=v"(r) : "v"(lo), "v"(hi));
    return r;
}

__device__ __forceinline__ v16f zero16() {
    v16f z;
#pragma unroll
    for (int i = 0; i < 16; ++i) z[i] = 0.f;
    return z;
}

// async global->LDS, 16B per lane; LDS dest = wave-uniform base + lane*16
#define GL16(g, l) __builtin_amdgcn_global_load_lds( \
    (__attribute__((address_space(1))) void*)(g),    \
    (__attribute__((address_space(3))) void*)(l), 16, 0, 0)

// Q is pre-scaled by log2(e)/sqrt(64) so attention uses raw v_exp_f32 (2^x)
#define QSCALE 0.18033688011f

// ---------- fused fp32 -> bf16 convert: x + Wq + Wk + Wv + Wo in one launch ----------
__global__ __launch_bounds__(256) void cvt_all(
    const float4* __restrict__ x,  const float4* __restrict__ wq,
    const float4* __restrict__ wk, const float4* __restrict__ wv,
    const float4* __restrict__ wo,
    ushort4* __restrict__ xb, ushort4* __restrict__ wqkv, ushort4* __restrict__ wob) {
    int i = blockIdx.x * 256 + threadIdx.x;          // 0 .. 3145728-1 (float4 units)
    const float4* s; ushort4* d; int off;
    if (i < 2097152) { s = x; d = xb; off = i; }
    else {
        int wdx = (i - 2097152) >> 18;               // 262144 float4 per weight
        off = (i - 2097152) & 262143;
        if      (wdx == 0) { s = wq; d = wqkv; }
        else if (wdx == 1) { s = wk; d = wqkv + 262144; }
        else if (wdx == 2) { s = wv; d = wqkv + 524288; }
        else               { s = wo; d = wob; }
    }
    float4 v = s[off];
    ushort4 o;
    o.x = f2bf(v.x); o.y = f2bf(v.y); o.z = f2bf(v.z); o.w = f2bf(v.w);
    d[off] = o;
}

// ---------- GEMM mainloop: C = A(MxK) * W(NxK)^T ----------
// block = 256 threads (4 waves), tile 128x128, K=1024. BK=64 (was 32): the
// m97-structure's known ~20% loss is the per-step vmcnt(0)+barrier drain;
// BK=64 halves the step count (16 vs 32) at identical total bytes/MFMAs.
// LDS rows are now 128 B -> would be a 16-way read conflict, so stage/read
// use the granule-XOR swizzle proven in attn: LDS slot s of row r holds
// global granule s^(r&7); reads fetch slot ((kk*4+lq)^(row&7)) -> 64-lane
// b128 read spreads 8 accesses/bank-quad = minimum-time, conflict-free.
// T1 XCD swizzle kept (R8: non-attn 177.7 -> 173.3 us); bxs/bys = swizzled
// tile coords; epilogues use bxs for role selection. Epilogues are R8-exact
// (scalar Q/K/V stores; R9's vectorized-swap epilogue cost ~11 us -> reverted).
#define GEMM_MAINLOOP(A_, W_)                                                          \
    __shared__ bf16_t SMEM[16384];                                                     \
    bf16_t* As = SMEM; bf16_t* Bs = SMEM + 8192;                                       \
    const int tid = threadIdx.x;                                                       \
    const int w = tid >> 6, lane = tid & 63;                                           \
    const int lrow = lane & 15, lq = lane >> 4;                                        \
    const int nwg_ = gridDim.x * gridDim.y;                                            \
    const int id_ = blockIdx.y * gridDim.x + blockIdx.x;                               \
    const int sid_ = (id_ & 7) * (nwg_ >> 3) + (id_ >> 3);                             \
    const int bxs = sid_ % gridDim.x, bys = sid_ / gridDim.x;                          \
    const int m0 = bys * 128, n0 = bxs * 128;                                          \
    const int svrow = lane >> 3;                  /* row within 8-row GL16 block */    \
    const int sg8 = ((lane & 7) ^ svrow) * 8;     /* swizzled source granule */        \
    const int rx = lrow & 7;                      /* read-side row&7 */                \
    const int wm = (w & 1) * 64, wn = (w >> 1) * 64;                                   \
    v4f acc[4][4];                                                                     \
    _Pragma("unroll") for (int i = 0; i < 4; ++i)                                      \
        _Pragma("unroll") for (int j = 0; j < 4; ++j)                                  \
            acc[i][j] = (v4f){0.f, 0.f, 0.f, 0.f};                                     \
    for (int k0 = 0; k0 < 1024; k0 += 64) {                                            \
        __syncthreads();                                                               \
        _Pragma("unroll") for (int ii = 0; ii < 4; ++ii) {                             \
            int r0 = w * 32 + ii * 8;                                                  \
            GL16(A_ + (size_t)(m0 + r0 + svrow) * 1024 + k0 + sg8, (char*)As + r0 * 128); \
            GL16(W_ + (size_t)(n0 + r0 + svrow) * 1024 + k0 + sg8, (char*)Bs + r0 * 128); \
        }                                                                              \
        __syncthreads();                                                               \
        bf16x8 af[4][2], bf[4][2];                                                     \
        _Pragma("unroll") for (int i = 0; i < 4; ++i)                                  \
            _Pragma("unroll") for (int kk = 0; kk < 2; ++kk) {                         \
                af[i][kk] = *(const bf16x8*)                                           \
                    &As[(wm + i * 16 + lrow) * 64 + (((kk * 4 + lq) ^ rx) * 8)];       \
                bf[i][kk] = *(const bf16x8*)                                           \
                    &Bs[(wn + i * 16 + lrow) * 64 + (((kk * 4 + lq) ^ rx) * 8)];       \
            }                                                                          \
        _Pragma("unroll") for (int kk = 0; kk < 2; ++kk)                               \
            _Pragma("unroll") for (int i = 0; i < 4; ++i)                              \
                _Pragma("unroll") for (int j = 0; j < 4; ++j)                          \
                    acc[i][j] = __builtin_amdgcn_mfma_f32_16x16x32_bf16(               \
                        af[i][kk], bf[j][kk], acc[i][j], 0, 0, 0);                     \
    }

// QKV projection. Epilogue: Q (pre-scaled QSCALE) / K scatter (tiles bxs<16),
// V tiles (bxs>=16) transpose 128x128 through LDS -> coalesced V^T (b,h,d,t) stores.
__global__ __launch_bounds__(256) void gemm_qkv_kernel(
    const bf16_t* __restrict__ A, const bf16_t* __restrict__ W,
    bf16_t* __restrict__ Qb, bf16_t* __restrict__ Kb, bf16_t* __restrict__ Vtb) {
    GEMM_MAINLOOP(A, W)
    const int x = bxs;                       // swizzled n-tile decides Q/K/V role
    const int b = m0 >> 12, t0 = m0 & 4095;
    if (x < 8) {
        // Q: (b,h,t,d), pre-scaled
#pragma unroll
        for (int i = 0; i < 4; ++i)
#pragma unroll
            for (int j = 0; j < 4; ++j)
#pragma unroll
                for (int r = 0; r < 4; ++r) {
                    int t = t0 + wm + i * 16 + lq * 4 + r;
                    int n = n0 + wn + j * 16 + lrow;
                    int h = n >> 6, d = n & 63;
                    Qb[(((size_t)b * 16 + h) * 4096 + t) * 64 + d] =
                        f2bf(acc[i][j][r] * QSCALE);
                }
    } else if (x < 16) {
        // K: (b,h,t,d)
#pragma unroll
        for (int i = 0; i < 4; ++i)
#pragma unroll
            for (int j = 0; j < 4; ++j)
#pragma unroll
                for (int r = 0; r < 4; ++r) {
                    int t = t0 + wm + i * 16 + lq * 4 + r;
                    int nn = n0 + wn + j * 16 + lrow - 1024;
                    int h = nn >> 6, d = nn & 63;
                    Kb[(((size_t)b * 16 + h) * 4096 + t) * 64 + d] = f2bf(acc[i][j][r]);
                }
    } else {
        // V: transpose through LDS (reusing SMEM, 64 n-rows x 128 m per pass),
        // xor-swizzled 8B granules -> 2-way banks; stores are 16B coalesced.
        const int d0 = n0 - 2048;
#pragma unroll 1
        for (int p = 0; p < 2; ++p) {
            __syncthreads();
            if ((w >> 1) == p) {
#pragma unroll
                for (int i = 0; i < 4; ++i)
#pragma unroll
                    for (int j = 0; j < 4; ++j) {
                        int row = j * 16 + lrow;
                        int swz = (row & 7) << 1;
                        int g = (wm >> 2) + i * 4 + lq;
                        uint2 u;
                        u.x = (unsigned)f2bf(acc[i][j][0]) | ((unsigned)f2bf(acc[i][j][1]) << 16);
                        u.y = (unsigned)f2bf(acc[i][j][2]) | ((unsigned)f2bf(acc[i][j][3]) << 16);
                        *(uint2*)&SMEM[row * 128 + ((g ^ swz) << 2)] = u;
                    }
            }
            __syncthreads();
#pragma unroll
            for (int uu = 0; uu < 4; ++uu) {
                int unit = tid + 256 * uu;           // 1024 units = 64 rows x 16 segs
                int row = unit >> 4, seg = unit & 15;
                uint4 val = *(const uint4*)&SMEM[row * 128 + ((seg ^ (row & 7)) << 3)];
                *(uint4*)&Vtb[((size_t)b * 1024 + d0 + p * 64 + row) * 4096 + t0 + seg * 8] = val;
            }
        }
    }
}

// Output projection: out = Ob(8192x1024) @ Wo^T + bo, fp32 out
__global__ __launch_bounds__(256) void gemm_out_kernel(
    const bf16_t* __restrict__ A, const bf16_t* __restrict__ W,
    const float* __restrict__ bo, float* __restrict__ out) {
    GEMM_MAINLOOP(A, W)
#pragma unroll
    for (int j = 0; j < 4; ++j) {
        int n = n0 + wn + j * 16 + lrow;
        float bias = bo[n];
#pragma unroll
        for (int i = 0; i < 4; ++i)
#pragma unroll
            for (int r = 0; r < 4; ++r) {
                int m = m0 + wm + i * 16 + lq * 4 + r;
                out[(size_t)m * 1024 + n] = acc[i][j][r] + bias;
            }
    }
}

// ---------- causal flash attention, v13 (FROZEN — structural floor) ----------
// v9 body + XCD-affine (g,bh) mapping (R9: FETCH 253->24.6 MB, dur 126.6->120.9).
// Occupancy (R2/R5/R6), pipelining (R1), setprio (R8) all measured-dead.
__global__ __launch_bounds__(256, 2) void attn_kernel(
    const bf16_t* __restrict__ Q, const bf16_t* __restrict__ K,
    const bf16_t* __restrict__ Vt, bf16_t* __restrict__ O) {
    __shared__ bf16_t Kls[2][64 * 64];   // [buf][t-row * 64d] swizzled, 8 KB/buf
    __shared__ bf16_t Vls[2][64 * 64];   // [buf][d-row * 64t] swizzled, 8 KB/buf
    const int tid = threadIdx.x;
    const int w = tid >> 6, lane = tid & 63;
    const int l31 = lane & 31, lh = lane >> 5;

    const int id = blockIdx.y * 16 + blockIdx.x;     // 0..511
    const int g = (id >> 3) & 15;                    // task-pair index 0..15
    const int bh = (id & 7) + ((id >> 7) << 3);      // XCD id%8 owns 4 bh

    const bf16_t* Qh = Q + (size_t)bh * (4096 * 64);
    const bf16_t* Kh = K + (size_t)bh * (4096 * 64);
    const bf16_t* Vh = Vt + (size_t)bh * (64 * 4096);
    const int b = bh >> 4, h = bh & 15;

    // staging: lane covers (row8 = lane>>3, slot = lane&7); slot s of row r
    // holds source granule s ^ (r&7); rows are 8 granules x 16B = 128 B
    const int svrow = lane >> 3;                 // row within 8-row GL16 block
    const int sg8 = ((lane & 7) ^ svrow) * 8;    // source granule elem offset
    const int rx = l31 & 7;                      // read-side row&7

    bf16x8 ones;
#pragma unroll
    for (int i = 0; i < 8; ++i) ones[i] = (__bf16)1.0f;

#pragma unroll 1
    for (int mem = 0; mem < 2; ++mem) {
        const int j = mem ? (31 - g) : g;   // 128-row task index (balanced pairs)
        const int q0 = j * 128;
        const int q0w = q0 + w * 32;        // this wave's 32 rows
        const int nt = 2 * j + 2;
        const int wlast = 2 * j + (w >> 1); // wave's diagonal tile
        const int qglob = q0w + l31;        // lane's q column

        bf16x8 qf[4];                       // B-operand: col q = l31, k = d
#pragma unroll
        for (int dk = 0; dk < 4; ++dk)
            qf[dk] = *(const bf16x8*)&Qh[(size_t)(q0w + l31) * 64 + dk * 16 + lh * 8];

        v16f oacc0 = zero16(), oacc1 = zero16(), lacc = zero16();

        // stage tile kt into buf: 16 GL16 (8 K + 8 V), 4 per wave
        auto stage = [&](int kt, int buf) {
            const int kc0 = kt << 6;
#pragma unroll
            for (int i = 0; i < 2; ++i) {
                int r0 = w * 16 + i * 8;
                GL16(Kh + (size_t)(kc0 + r0 + svrow) * 64 + sg8, (char*)&Kls[buf][r0 * 64]);
                GL16(Vh + (size_t)(r0 + svrow) * 4096 + kc0 + sg8, (char*)&Vls[buf][r0 * 64]);
            }
        };

        stage(0, 0);
        for (int kt = 0; kt < nt; ++kt) {
            const int buf = kt & 1;
            __syncthreads();                 // drains this wave's GL16s + all waves
            if (kt + 1 < nt) stage(kt + 1, buf ^ 1);
            if (kt > wlast) continue;        // fully-masked tile: loads+barriers only
            const int kc0 = kt << 6;
            const bool diag = (kt == wlast);

            // K fragments (A-operand: row t = th*32 + l31, k = d = dk*16+lh*8..)
            bf16x8 kf[2][4];
#pragma unroll
            for (int th = 0; th < 2; ++th)
#pragma unroll
                for (int dk = 0; dk < 4; ++dk)
                    kf[th][dk] = *(const bf16x8*)
                        &Kls[buf][(th * 32 + l31) * 64 + (((dk * 2 + lh) ^ rx) * 8)];
            // V fragments (B-operand: col d = db*32 + l31, k = t = kb*16+lh*8..)
            bf16x8 vf[2][4];
#pragma unroll
            for (int db = 0; db < 2; ++db)
#pragma unroll
                for (int kb = 0; kb < 4; ++kb)
                    vf[db][kb] = *(const bf16x8*)
                        &Vls[buf][(db * 32 + l31) * 64 + (((kb * 2 + lh) ^ rx) * 8)];

            // S^T = K Q^T, both t-halves interleaved (ILP 2)
            v16f st0 = zero16(), st1 = zero16();
#pragma unroll
            for (int dk = 0; dk < 4; ++dk) {
                st0 = __builtin_amdgcn_mfma_f32_32x32x16_bf16(kf[0][dk], qf[dk], st0, 0, 0, 0);
                st1 = __builtin_amdgcn_mfma_f32_32x32x16_bf16(kf[1][dk], qf[dk], st1, 0, 0, 0);
            }

            // P = 2^S (mask after exp on diag), packed to PV A-frags in-register.
            // Reg r of S^T holds t = th*32 + (r&3) + 8*(r>>2) + 4*lh.
            // A-frag kb needs t = kb*16 + lh*8 + j (j=0..7):
            //   dw0 = {base+8lh+0,1} dw1 = {+2,+3} dw2 = {+4,+5} dw3 = {+6,+7}.
            // x0/x1 = own low quad pairs, y0/y1 = own +8 quad pairs;
            // swap(x, y): ret.x = dw0/1 (lh0: own x; lh1: partner y),
            //             ret.y = dw2/3 (lh0: partner x; lh1: own y).
            bf16x8 pa[4];
#pragma unroll
            for (int th = 0; th < 2; ++th) {
                float p[16];
#pragma unroll
                for (int rr = 0; rr < 16; ++rr) {
                    float pv = __builtin_amdgcn_exp2f(th ? st1[rr] : st0[rr]);
                    if (diag) {
                        int tg = kc0 + th * 32 + (rr & 3) + 8 * (rr >> 2) + 4 * lh;
                        pv = (tg > qglob) ? 0.f : pv;
                    }
                    p[rr] = pv;
                }
#pragma unroll
                for (int kb2 = 0; kb2 < 2; ++kb2) {
                    unsigned x0 = cvtpk(p[kb2 * 8 + 0], p[kb2 * 8 + 1]);
                    unsigned x1 = cvtpk(p[kb2 * 8 + 2], p[kb2 * 8 + 3]);
                    unsigned y0 = cvtpk(p[kb2 * 8 + 4], p[kb2 * 8 + 5]);
                    unsigned y1 = cvtpk(p[kb2 * 8 + 6], p[kb2 * 8 + 7]);
                    u32x2 ra = __builtin_amdgcn_permlane32_swap(x0, y0, false, false);
                    u32x2 rb = __builtin_amdgcn_permlane32_swap(x1, y1, false, false);
                    union { unsigned u[4]; bf16x8 v; } pu;
                    pu.u[0] = ra.x; pu.u[1] = rb.x;   // t{base+8lh+0..3}
                    pu.u[2] = ra.y; pu.u[3] = rb.y;   // t{base+8lh+4..7}
                    pa[th * 2 + kb2] = pu.v;
                }
            }

            // l += P @ 1 ; O += P @ V
#pragma unroll
            for (int kb = 0; kb < 4; ++kb) {
                lacc  = __builtin_amdgcn_mfma_f32_32x32x16_bf16(pa[kb], ones,       lacc,  0, 0, 0);
                oacc0 = __builtin_amdgcn_mfma_f32_32x32x16_bf16(pa[kb], vf[0][kb], oacc0, 0, 0, 0);
                oacc1 = __builtin_amdgcn_mfma_f32_32x32x16_bf16(pa[kb], vf[1][kb], oacc1, 0, 0, 0);
            }
        }

        // epilogue: O = oacc / l  (lacc rows == oacc rows; any col holds the sum)
#pragma unroll
        for (int rr = 0; rr < 16; ++rr) {
            float rl = 1.0f / lacc[rr];
            int q = q0w + (rr & 3) + 8 * (rr >> 2) + 4 * lh;
            size_t o0 = ((size_t)b * 4096 + q) * 1024 + h * 64;
            O[o0 + l31]      = f2bf(oacc0[rr] * rl);
            O[o0 + 32 + l31] = f2bf(oacc1[rr] * rl);
        }
    }
}

// ---------- launch ----------
extern "C" void kernel_launch(void* const* d_in, const int* in_sizes, int n_in,
                              void* d_out, int out_size, void* d_ws, size_t ws_size,
                              hipStream_t stream) {
    const float* x  = (const float*)d_in[0];
    const float* Wq = (const float*)d_in[1];
    const float* Wk = (const float*)d_in[2];
    const float* Wv = (const float*)d_in[3];
    const float* Wo = (const float*)d_in[4];
    const float* bo = (const float*)d_in[5];
    float* out = (float*)d_out;

    char* ws = (char*)d_ws;
    bf16_t* xb   = (bf16_t*)(ws + 0);           // 8192x1024      16.78 MB
    bf16_t* Wqkv = (bf16_t*)(ws + 16777216);    // 3072x1024       6.29 MB
    bf16_t* Wob  = (bf16_t*)(ws + 23068672);    // 1024x1024       2.10 MB
    bf16_t* Qb   = (bf16_t*)(ws + 25165824);    // (b,h,t,d)      16.78 MB
    bf16_t* Kb   = (bf16_t*)(ws + 41943040);    // (b,h,t,d)      16.78 MB
    bf16_t* Vtb  = (bf16_t*)(ws + 58720256);    // (b,h,d,t)      16.78 MB
    bf16_t* Ob   = (bf16_t*)(ws + 75497472);    // 8192x1024      16.78 MB

    // fused converts (x, Wq, Wk, Wv, Wo) in one launch
    cvt_all<<<12288, 256, 0, stream>>>((const float4*)x, (const float4*)Wq,
                                       (const float4*)Wk, (const float4*)Wv,
                                       (const float4*)Wo,
                                       (ushort4*)xb, (ushort4*)Wqkv, (ushort4*)Wob);

    // QKV projection (M=8192, N=3072), XCD-swizzled grid, BK=64
    gemm_qkv_kernel<<<dim3(24, 64), 256, 0, stream>>>(xb, Wqkv, Qb, Kb, Vtb);

    // causal flash attention (v13, frozen)
    attn_kernel<<<dim3(16, 32), 256, 0, stream>>>(Qb, Kb, Vtb, Ob);

    // output projection (M=8192, N=1024) + bias, XCD-swizzled grid, BK=64
    gemm_out_kernel<<<dim3(8, 64), 256, 0, stream>>>(Ob, Wob, bo, out);
}

// Round 11
// 295.357 us; speedup vs baseline: 1.1608x; 1.1608x over previous
//
#include <hip/hip_runtime.h>

// ---------- types ----------
typedef unsigned short bf16_t;                                    // raw bf16 bits
typedef __bf16 bf16x8 __attribute__((ext_vector_type(8)));        // MFMA A/B frag (4 VGPRs)
typedef float  v4f   __attribute__((ext_vector_type(4)));         // 16x16 MFMA C/D frag
typedef float  v16f  __attribute__((ext_vector_type(16)));        // 32x32 MFMA C/D frag
typedef unsigned u32x2 __attribute__((ext_vector_type(2)));

// round-to-nearest-even f32 -> bf16 (branchless; inputs are finite)
__device__ __forceinline__ bf16_t f2bf(float f) {
    union { float f; unsigned u; } a; a.f = f;
    unsigned r = a.u + 0x7FFFu + ((a.u >> 16) & 1u);
    return (bf16_t)(r >> 16);
}

// pack two f32 -> bf16x2 dword (hardware RNE): low16 = bf16(lo), high16 = bf16(hi)
__device__ __forceinline__ unsigned cvtpk(float lo, float hi) {
    unsigned r;
    asm("v_cvt_pk_bf16_f32 %0, %1, %2" : "=v"(r) : "v"(lo), "v"(hi));
    return r;
}

__device__ __forceinline__ v16f zero16() {
    v16f z;
#pragma unroll
    for (int i = 0; i < 16; ++i) z[i] = 0.f;
    return z;
}

// async global->LDS, 16B per lane; LDS dest = wave-uniform base + lane*16
#define GL16(g, l) __builtin_amdgcn_global_load_lds( \
    (__attribute__((address_space(1))) void*)(g),    \
    (__attribute__((address_space(3))) void*)(l), 16, 0, 0)

// Q is pre-scaled by log2(e)/sqrt(64) so attention uses raw v_exp_f32 (2^x)
#define QSCALE 0.18033688011f

// ---------- fused fp32 -> bf16 convert: x + Wq + Wk + Wv + Wo in one launch ----------
__global__ __launch_bounds__(256) void cvt_all(
    const float4* __restrict__ x,  const float4* __restrict__ wq,
    const float4* __restrict__ wk, const float4* __restrict__ wv,
    const float4* __restrict__ wo,
    ushort4* __restrict__ xb, ushort4* __restrict__ wqkv, ushort4* __restrict__ wob) {
    int i = blockIdx.x * 256 + threadIdx.x;          // 0 .. 3145728-1 (float4 units)
    const float4* s; ushort4* d; int off;
    if (i < 2097152) { s = x; d = xb; off = i; }
    else {
        int wdx = (i - 2097152) >> 18;               // 262144 float4 per weight
        off = (i - 2097152) & 262143;
        if      (wdx == 0) { s = wq; d = wqkv; }
        else if (wdx == 1) { s = wk; d = wqkv + 262144; }
        else if (wdx == 2) { s = wv; d = wqkv + 524288; }
        else               { s = wo; d = wob; }
    }
    float4 v = s[off];
    ushort4 o;
    o.x = f2bf(v.x); o.y = f2bf(v.y); o.z = f2bf(v.z); o.w = f2bf(v.w);
    d[off] = o;
}

// ---------- GEMM mainloop (m97 structure, BK=32 — measured best): ----------
// C = A(MxK) * W(NxK)^T. block = 256 threads (4 waves), tile 128x128, K=1024.
// R10's BK=64 regressed (VGPR 96->136, occupancy 10.8%, gemm_qkv 129 us);
// R9's vectorized-swap epilogues regressed (+11 us). This is the R8 config:
// BK=32 + T1 XCD swizzle (bijective, nwg%8==0) + scalar epilogues.
// bxs/bys are SWIZZLED tile coords; epilogues use bxs for role selection.
#define GEMM_MAINLOOP(A_, W_)                                                          \
    __shared__ bf16_t SMEM[8192];                                                      \
    bf16_t* As = SMEM; bf16_t* Bs = SMEM + 4096;                                       \
    const int tid = threadIdx.x;                                                       \
    const int w = tid >> 6, lane = tid & 63;                                           \
    const int lrow = lane & 15, lq = lane >> 4;                                        \
    const int nwg_ = gridDim.x * gridDim.y;                                            \
    const int id_ = blockIdx.y * gridDim.x + blockIdx.x;                               \
    const int sid_ = (id_ & 7) * (nwg_ >> 3) + (id_ >> 3);                             \
    const int bxs = sid_ % gridDim.x, bys = sid_ / gridDim.x;                          \
    const int m0 = bys * 128, n0 = bxs * 128;                                          \
    const int srow = w * 16 + (lane >> 2);                                             \
    const int sk = (lane & 3) * 8;                                                     \
    const int wm = (w & 1) * 64, wn = (w >> 1) * 64;                                   \
    v4f acc[4][4];                                                                     \
    _Pragma("unroll") for (int i = 0; i < 4; ++i)                                      \
        _Pragma("unroll") for (int j = 0; j < 4; ++j)                                  \
            acc[i][j] = (v4f){0.f, 0.f, 0.f, 0.f};                                     \
    for (int k0 = 0; k0 < 1024; k0 += 32) {                                            \
        __syncthreads();                                                               \
        GL16(A_ + (size_t)(m0 + srow) * 1024 + k0 + sk,      (char*)As + w * 1024);    \
        GL16(A_ + (size_t)(m0 + 64 + srow) * 1024 + k0 + sk, (char*)As + 4096 + w * 1024); \
        GL16(W_ + (size_t)(n0 + srow) * 1024 + k0 + sk,      (char*)Bs + w * 1024);    \
        GL16(W_ + (size_t)(n0 + 64 + srow) * 1024 + k0 + sk, (char*)Bs + 4096 + w * 1024); \
        __syncthreads();                                                               \
        bf16x8 af[4], bf[4];                                                           \
        _Pragma("unroll") for (int i = 0; i < 4; ++i)                                  \
            af[i] = *(const bf16x8*)&As[(wm + i * 16 + lrow) * 32 + lq * 8];           \
        _Pragma("unroll") for (int j = 0; j < 4; ++j)                                  \
            bf[j] = *(const bf16x8*)&Bs[(wn + j * 16 + lrow) * 32 + lq * 8];           \
        _Pragma("unroll") for (int i = 0; i < 4; ++i)                                  \
            _Pragma("unroll") for (int j = 0; j < 4; ++j)                              \
                acc[i][j] = __builtin_amdgcn_mfma_f32_16x16x32_bf16(af[i], bf[j],      \
                                                                    acc[i][j], 0, 0, 0); \
    }

// QKV projection. Epilogue: Q (pre-scaled QSCALE) / K scatter (tiles bxs<16),
// V tiles (bxs>=16) transpose 128x128 through LDS -> coalesced V^T (b,h,d,t) stores.
__global__ __launch_bounds__(256) void gemm_qkv_kernel(
    const bf16_t* __restrict__ A, const bf16_t* __restrict__ W,
    bf16_t* __restrict__ Qb, bf16_t* __restrict__ Kb, bf16_t* __restrict__ Vtb) {
    GEMM_MAINLOOP(A, W)
    const int x = bxs;                       // swizzled n-tile decides Q/K/V role
    const int b = m0 >> 12, t0 = m0 & 4095;
    if (x < 8) {
        // Q: (b,h,t,d), pre-scaled
#pragma unroll
        for (int i = 0; i < 4; ++i)
#pragma unroll
            for (int j = 0; j < 4; ++j)
#pragma unroll
                for (int r = 0; r < 4; ++r) {
                    int t = t0 + wm + i * 16 + lq * 4 + r;
                    int n = n0 + wn + j * 16 + lrow;
                    int h = n >> 6, d = n & 63;
                    Qb[(((size_t)b * 16 + h) * 4096 + t) * 64 + d] =
                        f2bf(acc[i][j][r] * QSCALE);
                }
    } else if (x < 16) {
        // K: (b,h,t,d)
#pragma unroll
        for (int i = 0; i < 4; ++i)
#pragma unroll
            for (int j = 0; j < 4; ++j)
#pragma unroll
                for (int r = 0; r < 4; ++r) {
                    int t = t0 + wm + i * 16 + lq * 4 + r;
                    int nn = n0 + wn + j * 16 + lrow - 1024;
                    int h = nn >> 6, d = nn & 63;
                    Kb[(((size_t)b * 16 + h) * 4096 + t) * 64 + d] = f2bf(acc[i][j][r]);
                }
    } else {
        // V: transpose through LDS (reusing SMEM, 64 n-rows x 128 m per pass),
        // xor-swizzled 8B granules -> 2-way banks; stores are 16B coalesced.
        const int d0 = n0 - 2048;
#pragma unroll 1
        for (int p = 0; p < 2; ++p) {
            __syncthreads();
            if ((w >> 1) == p) {
#pragma unroll
                for (int i = 0; i < 4; ++i)
#pragma unroll
                    for (int j = 0; j < 4; ++j) {
                        int row = j * 16 + lrow;
                        int swz = (row & 7) << 1;
                        int g = (wm >> 2) + i * 4 + lq;
                        uint2 u;
                        u.x = (unsigned)f2bf(acc[i][j][0]) | ((unsigned)f2bf(acc[i][j][1]) << 16);
                        u.y = (unsigned)f2bf(acc[i][j][2]) | ((unsigned)f2bf(acc[i][j][3]) << 16);
                        *(uint2*)&SMEM[row * 128 + ((g ^ swz) << 2)] = u;
                    }
            }
            __syncthreads();
#pragma unroll
            for (int uu = 0; uu < 4; ++uu) {
                int unit = tid + 256 * uu;           // 1024 units = 64 rows x 16 segs
                int row = unit >> 4, seg = unit & 15;
                uint4 val = *(const uint4*)&SMEM[row * 128 + ((seg ^ (row & 7)) << 3)];
                *(uint4*)&Vtb[((size_t)b * 1024 + d0 + p * 64 + row) * 4096 + t0 + seg * 8] = val;
            }
        }
    }
}

// Output projection: out = Ob(8192x1024) @ Wo^T + bo, fp32 out
__global__ __launch_bounds__(256) void gemm_out_kernel(
    const bf16_t* __restrict__ A, const bf16_t* __restrict__ W,
    const float* __restrict__ bo, float* __restrict__ out) {
    GEMM_MAINLOOP(A, W)
#pragma unroll
    for (int j = 0; j < 4; ++j) {
        int n = n0 + wn + j * 16 + lrow;
        float bias = bo[n];
#pragma unroll
        for (int i = 0; i < 4; ++i)
#pragma unroll
            for (int r = 0; r < 4; ++r) {
                int m = m0 + wm + i * 16 + lq * 4 + r;
                out[(size_t)m * 1024 + n] = acc[i][j][r] + bias;
            }
    }
}

// ---------- causal flash attention, v13 (FROZEN — structural floor) ----------
// v9 body + XCD-affine (g,bh) mapping (R9: FETCH 253->24.6 MB, dur 126.6->120.9).
// Occupancy (R2/R5/R6), pipelining (R1), setprio (R8) all measured-dead.
__global__ __launch_bounds__(256, 2) void attn_kernel(
    const bf16_t* __restrict__ Q, const bf16_t* __restrict__ K,
    const bf16_t* __restrict__ Vt, bf16_t* __restrict__ O) {
    __shared__ bf16_t Kls[2][64 * 64];   // [buf][t-row * 64d] swizzled, 8 KB/buf
    __shared__ bf16_t Vls[2][64 * 64];   // [buf][d-row * 64t] swizzled, 8 KB/buf
    const int tid = threadIdx.x;
    const int w = tid >> 6, lane = tid & 63;
    const int l31 = lane & 31, lh = lane >> 5;

    const int id = blockIdx.y * 16 + blockIdx.x;     // 0..511
    const int g = (id >> 3) & 15;                    // task-pair index 0..15
    const int bh = (id & 7) + ((id >> 7) << 3);      // XCD id%8 owns 4 bh

    const bf16_t* Qh = Q + (size_t)bh * (4096 * 64);
    const bf16_t* Kh = K + (size_t)bh * (4096 * 64);
    const bf16_t* Vh = Vt + (size_t)bh * (64 * 4096);
    const int b = bh >> 4, h = bh & 15;

    // staging: lane covers (row8 = lane>>3, slot = lane&7); slot s of row r
    // holds source granule s ^ (r&7); rows are 8 granules x 16B = 128 B
    const int svrow = lane >> 3;                 // row within 8-row GL16 block
    const int sg8 = ((lane & 7) ^ svrow) * 8;    // source granule elem offset
    const int rx = l31 & 7;                      // read-side row&7

    bf16x8 ones;
#pragma unroll
    for (int i = 0; i < 8; ++i) ones[i] = (__bf16)1.0f;

#pragma unroll 1
    for (int mem = 0; mem < 2; ++mem) {
        const int j = mem ? (31 - g) : g;   // 128-row task index (balanced pairs)
        const int q0 = j * 128;
        const int q0w = q0 + w * 32;        // this wave's 32 rows
        const int nt = 2 * j + 2;
        const int wlast = 2 * j + (w >> 1); // wave's diagonal tile
        const int qglob = q0w + l31;        // lane's q column

        bf16x8 qf[4];                       // B-operand: col q = l31, k = d
#pragma unroll
        for (int dk = 0; dk < 4; ++dk)
            qf[dk] = *(const bf16x8*)&Qh[(size_t)(q0w + l31) * 64 + dk * 16 + lh * 8];

        v16f oacc0 = zero16(), oacc1 = zero16(), lacc = zero16();

        // stage tile kt into buf: 16 GL16 (8 K + 8 V), 4 per wave
        auto stage = [&](int kt, int buf) {
            const int kc0 = kt << 6;
#pragma unroll
            for (int i = 0; i < 2; ++i) {
                int r0 = w * 16 + i * 8;
                GL16(Kh + (size_t)(kc0 + r0 + svrow) * 64 + sg8, (char*)&Kls[buf][r0 * 64]);
                GL16(Vh + (size_t)(r0 + svrow) * 4096 + kc0 + sg8, (char*)&Vls[buf][r0 * 64]);
            }
        };

        stage(0, 0);
        for (int kt = 0; kt < nt; ++kt) {
            const int buf = kt & 1;
            __syncthreads();                 // drains this wave's GL16s + all waves
            if (kt + 1 < nt) stage(kt + 1, buf ^ 1);
            if (kt > wlast) continue;        // fully-masked tile: loads+barriers only
            const int kc0 = kt << 6;
            const bool diag = (kt == wlast);

            // K fragments (A-operand: row t = th*32 + l31, k = d = dk*16+lh*8..)
            bf16x8 kf[2][4];
#pragma unroll
            for (int th = 0; th < 2; ++th)
#pragma unroll
                for (int dk = 0; dk < 4; ++dk)
                    kf[th][dk] = *(const bf16x8*)
                        &Kls[buf][(th * 32 + l31) * 64 + (((dk * 2 + lh) ^ rx) * 8)];
            // V fragments (B-operand: col d = db*32 + l31, k = t = kb*16+lh*8..)
            bf16x8 vf[2][4];
#pragma unroll
            for (int db = 0; db < 2; ++db)
#pragma unroll
                for (int kb = 0; kb < 4; ++kb)
                    vf[db][kb] = *(const bf16x8*)
                        &Vls[buf][(db * 32 + l31) * 64 + (((kb * 2 + lh) ^ rx) * 8)];

            // S^T = K Q^T, both t-halves interleaved (ILP 2)
            v16f st0 = zero16(), st1 = zero16();
#pragma unroll
            for (int dk = 0; dk < 4; ++dk) {
                st0 = __builtin_amdgcn_mfma_f32_32x32x16_bf16(kf[0][dk], qf[dk], st0, 0, 0, 0);
                st1 = __builtin_amdgcn_mfma_f32_32x32x16_bf16(kf[1][dk], qf[dk], st1, 0, 0, 0);
            }

            // P = 2^S (mask after exp on diag), packed to PV A-frags in-register.
            // Reg r of S^T holds t = th*32 + (r&3) + 8*(r>>2) + 4*lh.
            // A-frag kb needs t = kb*16 + lh*8 + j (j=0..7):
            //   dw0 = {base+8lh+0,1} dw1 = {+2,+3} dw2 = {+4,+5} dw3 = {+6,+7}.
            // x0/x1 = own low quad pairs, y0/y1 = own +8 quad pairs;
            // swap(x, y): ret.x = dw0/1 (lh0: own x; lh1: partner y),
            //             ret.y = dw2/3 (lh0: partner x; lh1: own y).
            bf16x8 pa[4];
#pragma unroll
            for (int th = 0; th < 2; ++th) {
                float p[16];
#pragma unroll
                for (int rr = 0; rr < 16; ++rr) {
                    float pv = __builtin_amdgcn_exp2f(th ? st1[rr] : st0[rr]);
                    if (diag) {
                        int tg = kc0 + th * 32 + (rr & 3) + 8 * (rr >> 2) + 4 * lh;
                        pv = (tg > qglob) ? 0.f : pv;
                    }
                    p[rr] = pv;
                }
#pragma unroll
                for (int kb2 = 0; kb2 < 2; ++kb2) {
                    unsigned x0 = cvtpk(p[kb2 * 8 + 0], p[kb2 * 8 + 1]);
                    unsigned x1 = cvtpk(p[kb2 * 8 + 2], p[kb2 * 8 + 3]);
                    unsigned y0 = cvtpk(p[kb2 * 8 + 4], p[kb2 * 8 + 5]);
                    unsigned y1 = cvtpk(p[kb2 * 8 + 6], p[kb2 * 8 + 7]);
                    u32x2 ra = __builtin_amdgcn_permlane32_swap(x0, y0, false, false);
                    u32x2 rb = __builtin_amdgcn_permlane32_swap(x1, y1, false, false);
                    union { unsigned u[4]; bf16x8 v; } pu;
                    pu.u[0] = ra.x; pu.u[1] = rb.x;   // t{base+8lh+0..3}
                    pu.u[2] = ra.y; pu.u[3] = rb.y;   // t{base+8lh+4..7}
                    pa[th * 2 + kb2] = pu.v;
                }
            }

            // l += P @ 1 ; O += P @ V
#pragma unroll
            for (int kb = 0; kb < 4; ++kb) {
                lacc  = __builtin_amdgcn_mfma_f32_32x32x16_bf16(pa[kb], ones,       lacc,  0, 0, 0);
                oacc0 = __builtin_amdgcn_mfma_f32_32x32x16_bf16(pa[kb], vf[0][kb], oacc0, 0, 0, 0);
                oacc1 = __builtin_amdgcn_mfma_f32_32x32x16_bf16(pa[kb], vf[1][kb], oacc1, 0, 0, 0);
            }
        }

        // epilogue: O = oacc / l  (lacc rows == oacc rows; any col holds the sum)
#pragma unroll
        for (int rr = 0; rr < 16; ++rr) {
            float rl = 1.0f / lacc[rr];
            int q = q0w + (rr & 3) + 8 * (rr >> 2) + 4 * lh;
            size_t o0 = ((size_t)b * 4096 + q) * 1024 + h * 64;
            O[o0 + l31]      = f2bf(oacc0[rr] * rl);
            O[o0 + 32 + l31] = f2bf(oacc1[rr] * rl);
        }
    }
}

// ---------- launch ----------
extern "C" void kernel_launch(void* const* d_in, const int* in_sizes, int n_in,
                              void* d_out, int out_size, void* d_ws, size_t ws_size,
                              hipStream_t stream) {
    const float* x  = (const float*)d_in[0];
    const float* Wq = (const float*)d_in[1];
    const float* Wk = (const float*)d_in[2];
    const float* Wv = (const float*)d_in[3];
    const float* Wo = (const float*)d_in[4];
    const float* bo = (const float*)d_in[5];
    float* out = (float*)d_out;

    char* ws = (char*)d_ws;
    bf16_t* xb   = (bf16_t*)(ws + 0);           // 8192x1024      16.78 MB
    bf16_t* Wqkv = (bf16_t*)(ws + 16777216);    // 3072x1024       6.29 MB
    bf16_t* Wob  = (bf16_t*)(ws + 23068672);    // 1024x1024       2.10 MB
    bf16_t* Qb   = (bf16_t*)(ws + 25165824);    // (b,h,t,d)      16.78 MB
    bf16_t* Kb   = (bf16_t*)(ws + 41943040);    // (b,h,t,d)      16.78 MB
    bf16_t* Vtb  = (bf16_t*)(ws + 58720256);    // (b,h,d,t)      16.78 MB
    bf16_t* Ob   = (bf16_t*)(ws + 75497472);    // 8192x1024      16.78 MB

    // fused converts (x, Wq, Wk, Wv, Wo) in one launch
    cvt_all<<<12288, 256, 0, stream>>>((const float4*)x, (const float4*)Wq,
                                       (const float4*)Wk, (const float4*)Wv,
                                       (const float4*)Wo,
                                       (ushort4*)xb, (ushort4*)Wqkv, (ushort4*)Wob);

    // QKV projection (M=8192, N=3072), BK=32, XCD-swizzled grid
    gemm_qkv_kernel<<<dim3(24, 64), 256, 0, stream>>>(xb, Wqkv, Qb, Kb, Vtb);

    // causal flash attention (v13, frozen)
    attn_kernel<<<dim3(16, 32), 256, 0, stream>>>(Qb, Kb, Vtb, Ob);

    // output projection (M=8192, N=1024) + bias, BK=32, XCD-swizzled grid
    gemm_out_kernel<<<dim3(8, 64), 256, 0, stream>>>(Ob, Wob, bo, out);
}

// Round 12
// 290.922 us; speedup vs baseline: 1.1785x; 1.0152x over previous
//
#include <hip/hip_runtime.h>

// ---------- types ----------
typedef unsigned short bf16_t;                                    // raw bf16 bits
typedef __bf16 bf16x8 __attribute__((ext_vector_type(8)));        // MFMA A/B frag (4 VGPRs)
typedef float  v4f   __attribute__((ext_vector_type(4)));         // 16x16 MFMA C/D frag
typedef float  v16f  __attribute__((ext_vector_type(16)));        // 32x32 MFMA C/D frag
typedef unsigned u32x2 __attribute__((ext_vector_type(2)));

// round-to-nearest-even f32 -> bf16 (branchless; inputs are finite)
__device__ __forceinline__ bf16_t f2bf(float f) {
    union { float f; unsigned u; } a; a.f = f;
    unsigned r = a.u + 0x7FFFu + ((a.u >> 16) & 1u);
    return (bf16_t)(r >> 16);
}

// pack two f32 -> bf16x2 dword (hardware RNE): low16 = bf16(lo), high16 = bf16(hi)
__device__ __forceinline__ unsigned cvtpk(float lo, float hi) {
    unsigned r;
    asm("v_cvt_pk_bf16_f32 %0, %1, %2" : "=v"(r) : "v"(lo), "v"(hi));
    return r;
}

__device__ __forceinline__ v16f zero16() {
    v16f z;
#pragma unroll
    for (int i = 0; i < 16; ++i) z[i] = 0.f;
    return z;
}

// async global->LDS, 16B per lane; LDS dest = wave-uniform base + lane*16
#define GL16(g, l) __builtin_amdgcn_global_load_lds( \
    (__attribute__((address_space(1))) void*)(g),    \
    (__attribute__((address_space(3))) void*)(l), 16, 0, 0)

// Q is pre-scaled by log2(e)/sqrt(64) so attention uses raw v_exp_f32 (2^x)
#define QSCALE 0.18033688011f

// ---------- fused fp32 -> bf16 convert: x + Wq + Wk + Wv + Wo in one launch ----------
__global__ __launch_bounds__(256) void cvt_all(
    const float4* __restrict__ x,  const float4* __restrict__ wq,
    const float4* __restrict__ wk, const float4* __restrict__ wv,
    const float4* __restrict__ wo,
    ushort4* __restrict__ xb, ushort4* __restrict__ wqkv, ushort4* __restrict__ wob) {
    int i = blockIdx.x * 256 + threadIdx.x;          // 0 .. 3145728-1 (float4 units)
    const float4* s; ushort4* d; int off;
    if (i < 2097152) { s = x; d = xb; off = i; }
    else {
        int wdx = (i - 2097152) >> 18;               // 262144 float4 per weight
        off = (i - 2097152) & 262143;
        if      (wdx == 0) { s = wq; d = wqkv; }
        else if (wdx == 1) { s = wk; d = wqkv + 262144; }
        else if (wdx == 2) { s = wv; d = wqkv + 524288; }
        else               { s = wo; d = wob; }
    }
    float4 v = s[off];
    ushort4 o;
    o.x = f2bf(v.x); o.y = f2bf(v.y); o.z = f2bf(v.z); o.w = f2bf(v.w);
    d[off] = o;
}

// ---------- QKV projection: 256x128 tile, 512 threads (8 waves, 4m x 2n) ----------
// Theory (R12): W = 6.3 MB > 4 MB per-XCD L2, so the 128-tile grid streamed
// ~400 MB of W through L3/HBM (once per m-row). 256-m tiles + 2D XCD swizzle
// (each XCD: 4 m-tiles x 24 n-tiles; the 4 co-resident m-blocks of a W-tile
// share one L2 window) cut W L2-miss traffic to ~50 MB. Same BK=32 2-barrier
// loop, same per-wave 64x64 quadrant (acc[4][4], VGPR ~96, 2 blocks/CU).
__global__ __launch_bounds__(512, 4) void gemm_qkv_kernel(
    const bf16_t* __restrict__ A, const bf16_t* __restrict__ W,
    bf16_t* __restrict__ Qb, bf16_t* __restrict__ Kb, bf16_t* __restrict__ Vtb) {
    __shared__ bf16_t SMEM[16384];                 // 32 KB: As 16K + Bs 8K; V-xpose uses all
    bf16_t* As = SMEM;                             // [256][32]
    bf16_t* Bs = SMEM + 8192;                      // [128][32]
    const int tid = threadIdx.x;
    const int w = tid >> 6, lane = tid & 63;
    const int lrow = lane & 15, lq = lane >> 4;
    // 2D XCD swizzle: id -> xcd = id&7, r = id>>3; bys = xcd*4 + (r&3) (A-slice
    // 4x256 rows = 2.1 MB, L2-fit), bxs = r>>2 (all 24 n-tiles per XCD).
    const int id_ = blockIdx.y * 24 + blockIdx.x;
    const int xcd_ = id_ & 7, r_ = id_ >> 3;
    const int bys = xcd_ * 4 + (r_ & 3), bxs = r_ >> 2;
    const int m0 = bys * 256, n0 = bxs * 128;
    const int srw = lane >> 2;                     // staging row-within-unit 0..15
    const int sk = (lane & 3) * 8;                 // staging k-chunk
    const int wm = (w & 3) * 64, wn = (w >> 2) * 64;
    v4f acc[4][4];
#pragma unroll
    for (int i = 0; i < 4; ++i)
#pragma unroll
        for (int j = 0; j < 4; ++j) acc[i][j] = (v4f){0.f, 0.f, 0.f, 0.f};

    for (int k0 = 0; k0 < 1024; k0 += 32) {
        __syncthreads();
        // 24 wave-GL16 units (16 A + 8 B), 3 per wave; unit u stages 16 rows x 32 k
#pragma unroll
        for (int c = 0; c < 3; ++c) {
            int u = w * 3 + c;
            if (u < 16)
                GL16(A + (size_t)(m0 + u * 16 + srw) * 1024 + k0 + sk, (char*)As + u * 1024);
            else
                GL16(W + (size_t)(n0 + (u - 16) * 16 + srw) * 1024 + k0 + sk,
                     (char*)Bs + (u - 16) * 1024);
        }
        __syncthreads();
        bf16x8 af[4], bf[4];
#pragma unroll
        for (int i = 0; i < 4; ++i)
            af[i] = *(const bf16x8*)&As[(wm + i * 16 + lrow) * 32 + lq * 8];
#pragma unroll
        for (int j = 0; j < 4; ++j)
            bf[j] = *(const bf16x8*)&Bs[(wn + j * 16 + lrow) * 32 + lq * 8];
#pragma unroll
        for (int i = 0; i < 4; ++i)
#pragma unroll
            for (int j = 0; j < 4; ++j)
                acc[i][j] = __builtin_amdgcn_mfma_f32_16x16x32_bf16(af[i], bf[j],
                                                                    acc[i][j], 0, 0, 0);
    }

    const int x = bxs;                       // swizzled n-tile decides Q/K/V role
    const int b = m0 >> 12, t0 = m0 & 4095;  // 4096 % 256 == 0: tile never crosses batch
    if (x < 8) {
        // Q: (b,h,t,d), pre-scaled
#pragma unroll
        for (int i = 0; i < 4; ++i)
#pragma unroll
            for (int j = 0; j < 4; ++j)
#pragma unroll
                for (int r = 0; r < 4; ++r) {
                    int t = t0 + wm + i * 16 + lq * 4 + r;
                    int n = n0 + wn + j * 16 + lrow;
                    int h = n >> 6, d = n & 63;
                    Qb[(((size_t)b * 16 + h) * 4096 + t) * 64 + d] =
                        f2bf(acc[i][j][r] * QSCALE);
                }
    } else if (x < 16) {
        // K: (b,h,t,d)
#pragma unroll
        for (int i = 0; i < 4; ++i)
#pragma unroll
            for (int j = 0; j < 4; ++j)
#pragma unroll
                for (int r = 0; r < 4; ++r) {
                    int t = t0 + wm + i * 16 + lq * 4 + r;
                    int nn = n0 + wn + j * 16 + lrow - 1024;
                    int h = nn >> 6, d = nn & 63;
                    Kb[(((size_t)b * 16 + h) * 4096 + t) * 64 + d] = f2bf(acc[i][j][r]);
                }
    } else {
        // V: transpose through LDS (64 n-rows x 256 m per pass, 32 KB),
        // xor-swizzled 8B granules; stores are 16B coalesced along t.
        const int d0 = n0 - 2048;
#pragma unroll 1
        for (int p = 0; p < 2; ++p) {
            __syncthreads();
            if ((w >> 2) == p) {             // the 4 waves holding n-half p
#pragma unroll
                for (int i = 0; i < 4; ++i)
#pragma unroll
                    for (int j = 0; j < 4; ++j) {
                        int row = j * 16 + lrow;            // n-local 0..63
                        int swz = (row & 7) << 1;
                        int g = (wm >> 2) + i * 4 + lq;     // m-granule 0..63
                        uint2 u;
                        u.x = (unsigned)f2bf(acc[i][j][0]) | ((unsigned)f2bf(acc[i][j][1]) << 16);
                        u.y = (unsigned)f2bf(acc[i][j][2]) | ((unsigned)f2bf(acc[i][j][3]) << 16);
                        *(uint2*)&SMEM[row * 256 + ((g ^ swz) << 2)] = u;
                    }
            }
            __syncthreads();
#pragma unroll
            for (int uu = 0; uu < 4; ++uu) {
                int unit = tid + 512 * uu;           // 2048 units = 64 rows x 32 segs
                int row = unit >> 5, seg = unit & 31;
                uint4 val = *(const uint4*)&SMEM[row * 256 + ((seg ^ (row & 7)) << 3)];
                *(uint4*)&Vtb[((size_t)b * 1024 + d0 + p * 64 + row) * 4096 + t0 + seg * 8] = val;
            }
        }
    }
}

// ---------- GEMM mainloop (m97 structure, BK=32) for gemm_out ----------
// Wo = 2.1 MB already L2-fits per XCD; kernel kept at the measured-best R8
// config (128x128, 4 waves, T1 XCD swizzle, scalar epilogue).
#define GEMM_MAINLOOP(A_, W_)                                                          \
    __shared__ bf16_t SMEM[8192];                                                      \
    bf16_t* As = SMEM; bf16_t* Bs = SMEM + 4096;                                       \
    const int tid = threadIdx.x;                                                       \
    const int w = tid >> 6, lane = tid & 63;                                           \
    const int lrow = lane & 15, lq = lane >> 4;                                        \
    const int nwg_ = gridDim.x * gridDim.y;                                            \
    const int id_ = blockIdx.y * gridDim.x + blockIdx.x;                               \
    const int sid_ = (id_ & 7) * (nwg_ >> 3) + (id_ >> 3);                             \
    const int bxs = sid_ % gridDim.x, bys = sid_ / gridDim.x;                          \
    const int m0 = bys * 128, n0 = bxs * 128;                                          \
    const int srow = w * 16 + (lane >> 2);                                             \
    const int sk = (lane & 3) * 8;                                                     \
    const int wm = (w & 1) * 64, wn = (w >> 1) * 64;                                   \
    v4f acc[4][4];                                                                     \
    _Pragma("unroll") for (int i = 0; i < 4; ++i)                                      \
        _Pragma("unroll") for (int j = 0; j < 4; ++j)                                  \
            acc[i][j] = (v4f){0.f, 0.f, 0.f, 0.f};                                     \
    for (int k0 = 0; k0 < 1024; k0 += 32) {                                            \
        __syncthreads();                                                               \
        GL16(A_ + (size_t)(m0 + srow) * 1024 + k0 + sk,      (char*)As + w * 1024);    \
        GL16(A_ + (size_t)(m0 + 64 + srow) * 1024 + k0 + sk, (char*)As + 4096 + w * 1024); \
        GL16(W_ + (size_t)(n0 + srow) * 1024 + k0 + sk,      (char*)Bs + w * 1024);    \
        GL16(W_ + (size_t)(n0 + 64 + srow) * 1024 + k0 + sk, (char*)Bs + 4096 + w * 1024); \
        __syncthreads();                                                               \
        bf16x8 af[4], bf[4];                                                           \
        _Pragma("unroll") for (int i = 0; i < 4; ++i)                                  \
            af[i] = *(const bf16x8*)&As[(wm + i * 16 + lrow) * 32 + lq * 8];           \
        _Pragma("unroll") for (int j = 0; j < 4; ++j)                                  \
            bf[j] = *(const bf16x8*)&Bs[(wn + j * 16 + lrow) * 32 + lq * 8];           \
        _Pragma("unroll") for (int i = 0; i < 4; ++i)                                  \
            _Pragma("unroll") for (int j = 0; j < 4; ++j)                              \
                acc[i][j] = __builtin_amdgcn_mfma_f32_16x16x32_bf16(af[i], bf[j],      \
                                                                    acc[i][j], 0, 0, 0); \
    }

// Output projection: out = Ob(8192x1024) @ Wo^T + bo, fp32 out
__global__ __launch_bounds__(256) void gemm_out_kernel(
    const bf16_t* __restrict__ A, const bf16_t* __restrict__ W,
    const float* __restrict__ bo, float* __restrict__ out) {
    GEMM_MAINLOOP(A, W)
#pragma unroll
    for (int j = 0; j < 4; ++j) {
        int n = n0 + wn + j * 16 + lrow;
        float bias = bo[n];
#pragma unroll
        for (int i = 0; i < 4; ++i)
#pragma unroll
            for (int r = 0; r < 4; ++r) {
                int m = m0 + wm + i * 16 + lq * 4 + r;
                out[(size_t)m * 1024 + n] = acc[i][j][r] + bias;
            }
    }
}

// ---------- causal flash attention, v13 (FROZEN — structural floor) ----------
// v9 body + XCD-affine (g,bh) mapping (R9: FETCH 253->24.6 MB, dur 126.6->120.9).
// Occupancy (R2/R5/R6), pipelining (R1), setprio (R8) all measured-dead.
__global__ __launch_bounds__(256, 2) void attn_kernel(
    const bf16_t* __restrict__ Q, const bf16_t* __restrict__ K,
    const bf16_t* __restrict__ Vt, bf16_t* __restrict__ O) {
    __shared__ bf16_t Kls[2][64 * 64];   // [buf][t-row * 64d] swizzled, 8 KB/buf
    __shared__ bf16_t Vls[2][64 * 64];   // [buf][d-row * 64t] swizzled, 8 KB/buf
    const int tid = threadIdx.x;
    const int w = tid >> 6, lane = tid & 63;
    const int l31 = lane & 31, lh = lane >> 5;

    const int id = blockIdx.y * 16 + blockIdx.x;     // 0..511
    const int g = (id >> 3) & 15;                    // task-pair index 0..15
    const int bh = (id & 7) + ((id >> 7) << 3);      // XCD id%8 owns 4 bh

    const bf16_t* Qh = Q + (size_t)bh * (4096 * 64);
    const bf16_t* Kh = K + (size_t)bh * (4096 * 64);
    const bf16_t* Vh = Vt + (size_t)bh * (64 * 4096);
    const int b = bh >> 4, h = bh & 15;

    // staging: lane covers (row8 = lane>>3, slot = lane&7); slot s of row r
    // holds source granule s ^ (r&7); rows are 8 granules x 16B = 128 B
    const int svrow = lane >> 3;                 // row within 8-row GL16 block
    const int sg8 = ((lane & 7) ^ svrow) * 8;    // source granule elem offset
    const int rx = l31 & 7;                      // read-side row&7

    bf16x8 ones;
#pragma unroll
    for (int i = 0; i < 8; ++i) ones[i] = (__bf16)1.0f;

#pragma unroll 1
    for (int mem = 0; mem < 2; ++mem) {
        const int j = mem ? (31 - g) : g;   // 128-row task index (balanced pairs)
        const int q0 = j * 128;
        const int q0w = q0 + w * 32;        // this wave's 32 rows
        const int nt = 2 * j + 2;
        const int wlast = 2 * j + (w >> 1); // wave's diagonal tile
        const int qglob = q0w + l31;        // lane's q column

        bf16x8 qf[4];                       // B-operand: col q = l31, k = d
#pragma unroll
        for (int dk = 0; dk < 4; ++dk)
            qf[dk] = *(const bf16x8*)&Qh[(size_t)(q0w + l31) * 64 + dk * 16 + lh * 8];

        v16f oacc0 = zero16(), oacc1 = zero16(), lacc = zero16();

        // stage tile kt into buf: 16 GL16 (8 K + 8 V), 4 per wave
        auto stage = [&](int kt, int buf) {
            const int kc0 = kt << 6;
#pragma unroll
            for (int i = 0; i < 2; ++i) {
                int r0 = w * 16 + i * 8;
                GL16(Kh + (size_t)(kc0 + r0 + svrow) * 64 + sg8, (char*)&Kls[buf][r0 * 64]);
                GL16(Vh + (size_t)(r0 + svrow) * 4096 + kc0 + sg8, (char*)&Vls[buf][r0 * 64]);
            }
        };

        stage(0, 0);
        for (int kt = 0; kt < nt; ++kt) {
            const int buf = kt & 1;
            __syncthreads();                 // drains this wave's GL16s + all waves
            if (kt + 1 < nt) stage(kt + 1, buf ^ 1);
            if (kt > wlast) continue;        // fully-masked tile: loads+barriers only
            const int kc0 = kt << 6;
            const bool diag = (kt == wlast);

            // K fragments (A-operand: row t = th*32 + l31, k = d = dk*16+lh*8..)
            bf16x8 kf[2][4];
#pragma unroll
            for (int th = 0; th < 2; ++th)
#pragma unroll
                for (int dk = 0; dk < 4; ++dk)
                    kf[th][dk] = *(const bf16x8*)
                        &Kls[buf][(th * 32 + l31) * 64 + (((dk * 2 + lh) ^ rx) * 8)];
            // V fragments (B-operand: col d = db*32 + l31, k = t = kb*16+lh*8..)
            bf16x8 vf[2][4];
#pragma unroll
            for (int db = 0; db < 2; ++db)
#pragma unroll
                for (int kb = 0; kb < 4; ++kb)
                    vf[db][kb] = *(const bf16x8*)
                        &Vls[buf][(db * 32 + l31) * 64 + (((kb * 2 + lh) ^ rx) * 8)];

            // S^T = K Q^T, both t-halves interleaved (ILP 2)
            v16f st0 = zero16(), st1 = zero16();
#pragma unroll
            for (int dk = 0; dk < 4; ++dk) {
                st0 = __builtin_amdgcn_mfma_f32_32x32x16_bf16(kf[0][dk], qf[dk], st0, 0, 0, 0);
                st1 = __builtin_amdgcn_mfma_f32_32x32x16_bf16(kf[1][dk], qf[dk], st1, 0, 0, 0);
            }

            // P = 2^S (mask after exp on diag), packed to PV A-frags in-register.
            // Reg r of S^T holds t = th*32 + (r&3) + 8*(r>>2) + 4*lh.
            // A-frag kb needs t = kb*16 + lh*8 + j (j=0..7):
            //   dw0 = {base+8lh+0,1} dw1 = {+2,+3} dw2 = {+4,+5} dw3 = {+6,+7}.
            // x0/x1 = own low quad pairs, y0/y1 = own +8 quad pairs;
            // swap(x, y): ret.x = dw0/1 (lh0: own x; lh1: partner y),
            //             ret.y = dw2/3 (lh0: partner x; lh1: own y).
            bf16x8 pa[4];
#pragma unroll
            for (int th = 0; th < 2; ++th) {
                float p[16];
#pragma unroll
                for (int rr = 0; rr < 16; ++rr) {
                    float pv = __builtin_amdgcn_exp2f(th ? st1[rr] : st0[rr]);
                    if (diag) {
                        int tg = kc0 + th * 32 + (rr & 3) + 8 * (rr >> 2) + 4 * lh;
                        pv = (tg > qglob) ? 0.f : pv;
                    }
                    p[rr] = pv;
                }
#pragma unroll
                for (int kb2 = 0; kb2 < 2; ++kb2) {
                    unsigned x0 = cvtpk(p[kb2 * 8 + 0], p[kb2 * 8 + 1]);
                    unsigned x1 = cvtpk(p[kb2 * 8 + 2], p[kb2 * 8 + 3]);
                    unsigned y0 = cvtpk(p[kb2 * 8 + 4], p[kb2 * 8 + 5]);
                    unsigned y1 = cvtpk(p[kb2 * 8 + 6], p[kb2 * 8 + 7]);
                    u32x2 ra = __builtin_amdgcn_permlane32_swap(x0, y0, false, false);
                    u32x2 rb = __builtin_amdgcn_permlane32_swap(x1, y1, false, false);
                    union { unsigned u[4]; bf16x8 v; } pu;
                    pu.u[0] = ra.x; pu.u[1] = rb.x;   // t{base+8lh+0..3}
                    pu.u[2] = ra.y; pu.u[3] = rb.y;   // t{base+8lh+4..7}
                    pa[th * 2 + kb2] = pu.v;
                }
            }

            // l += P @ 1 ; O += P @ V
#pragma unroll
            for (int kb = 0; kb < 4; ++kb) {
                lacc  = __builtin_amdgcn_mfma_f32_32x32x16_bf16(pa[kb], ones,       lacc,  0, 0, 0);
                oacc0 = __builtin_amdgcn_mfma_f32_32x32x16_bf16(pa[kb], vf[0][kb], oacc0, 0, 0, 0);
                oacc1 = __builtin_amdgcn_mfma_f32_32x32x16_bf16(pa[kb], vf[1][kb], oacc1, 0, 0, 0);
            }
        }

        // epilogue: O = oacc / l  (lacc rows == oacc rows; any col holds the sum)
#pragma unroll
        for (int rr = 0; rr < 16; ++rr) {
            float rl = 1.0f / lacc[rr];
            int q = q0w + (rr & 3) + 8 * (rr >> 2) + 4 * lh;
            size_t o0 = ((size_t)b * 4096 + q) * 1024 + h * 64;
            O[o0 + l31]      = f2bf(oacc0[rr] * rl);
            O[o0 + 32 + l31] = f2bf(oacc1[rr] * rl);
        }
    }
}

// ---------- launch ----------
extern "C" void kernel_launch(void* const* d_in, const int* in_sizes, int n_in,
                              void* d_out, int out_size, void* d_ws, size_t ws_size,
                              hipStream_t stream) {
    const float* x  = (const float*)d_in[0];
    const float* Wq = (const float*)d_in[1];
    const float* Wk = (const float*)d_in[2];
    const float* Wv = (const float*)d_in[3];
    const float* Wo = (const float*)d_in[4];
    const float* bo = (const float*)d_in[5];
    float* out = (float*)d_out;

    char* ws = (char*)d_ws;
    bf16_t* xb   = (bf16_t*)(ws + 0);           // 8192x1024      16.78 MB
    bf16_t* Wqkv = (bf16_t*)(ws + 16777216);    // 3072x1024       6.29 MB
    bf16_t* Wob  = (bf16_t*)(ws + 23068672);    // 1024x1024       2.10 MB
    bf16_t* Qb   = (bf16_t*)(ws + 25165824);    // (b,h,t,d)      16.78 MB
    bf16_t* Kb   = (bf16_t*)(ws + 41943040);    // (b,h,t,d)      16.78 MB
    bf16_t* Vtb  = (bf16_t*)(ws + 58720256);    // (b,h,d,t)      16.78 MB
    bf16_t* Ob   = (bf16_t*)(ws + 75497472);    // 8192x1024      16.78 MB

    // fused converts (x, Wq, Wk, Wv, Wo) in one launch
    cvt_all<<<12288, 256, 0, stream>>>((const float4*)x, (const float4*)Wq,
                                       (const float4*)Wk, (const float4*)Wv,
                                       (const float4*)Wo,
                                       (ushort4*)xb, (ushort4*)Wqkv, (ushort4*)Wob);

    // QKV projection (M=8192, N=3072): 256x128 tiles, 512 threads, 2D XCD swizzle
    gemm_qkv_kernel<<<dim3(24, 32), 512, 0, stream>>>(xb, Wqkv, Qb, Kb, Vtb);

    // causal flash attention (v13, frozen)
    attn_kernel<<<dim3(16, 32), 256, 0, stream>>>(Qb, Kb, Vtb, Ob);

    // output projection (M=8192, N=1024) + bias, BK=32, XCD-swizzled grid
    gemm_out_kernel<<<dim3(8, 64), 256, 0, stream>>>(Ob, Wob, bo, out);
}

// Round 13
// 285.722 us; speedup vs baseline: 1.1999x; 1.0182x over previous
//
#include <hip/hip_runtime.h>

// ---------- types ----------
typedef unsigned short bf16_t;                                    // raw bf16 bits
typedef __bf16 bf16x8 __attribute__((ext_vector_type(8)));        // MFMA A/B frag (4 VGPRs)
typedef float  v4f   __attribute__((ext_vector_type(4)));         // 16x16 MFMA C/D frag
typedef float  v16f  __attribute__((ext_vector_type(16)));        // 32x32 MFMA C/D frag
typedef unsigned u32x2 __attribute__((ext_vector_type(2)));

// round-to-nearest-even f32 -> bf16 (branchless; inputs are finite)
__device__ __forceinline__ bf16_t f2bf(float f) {
    union { float f; unsigned u; } a; a.f = f;
    unsigned r = a.u + 0x7FFFu + ((a.u >> 16) & 1u);
    return (bf16_t)(r >> 16);
}

// pack two f32 -> bf16x2 dword (hardware RNE): low16 = bf16(lo), high16 = bf16(hi)
__device__ __forceinline__ unsigned cvtpk(float lo, float hi) {
    unsigned r;
    asm("v_cvt_pk_bf16_f32 %0, %1, %2" : "=v"(r) : "v"(lo), "v"(hi));
    return r;
}

__device__ __forceinline__ v16f zero16() {
    v16f z;
#pragma unroll
    for (int i = 0; i < 16; ++i) z[i] = 0.f;
    return z;
}

// async global->LDS, 16B per lane; LDS dest = wave-uniform base + lane*16
#define GL16(g, l) __builtin_amdgcn_global_load_lds( \
    (__attribute__((address_space(1))) void*)(g),    \
    (__attribute__((address_space(3))) void*)(l), 16, 0, 0)

// Q is pre-scaled by log2(e)/sqrt(64) so attention uses raw v_exp_f32 (2^x)
#define QSCALE 0.18033688011f

// ---------- fused fp32 -> bf16 convert: x + Wq + Wk + Wv + Wo in one launch ----------
__global__ __launch_bounds__(256) void cvt_all(
    const float4* __restrict__ x,  const float4* __restrict__ wq,
    const float4* __restrict__ wk, const float4* __restrict__ wv,
    const float4* __restrict__ wo,
    ushort4* __restrict__ xb, ushort4* __restrict__ wqkv, ushort4* __restrict__ wob) {
    int i = blockIdx.x * 256 + threadIdx.x;          // 0 .. 3145728-1 (float4 units)
    const float4* s; ushort4* d; int off;
    if (i < 2097152) { s = x; d = xb; off = i; }
    else {
        int wdx = (i - 2097152) >> 18;               // 262144 float4 per weight
        off = (i - 2097152) & 262143;
        if      (wdx == 0) { s = wq; d = wqkv; }
        else if (wdx == 1) { s = wk; d = wqkv + 262144; }
        else if (wdx == 2) { s = wv; d = wqkv + 524288; }
        else               { s = wo; d = wob; }
    }
    float4 v = s[off];
    ushort4 o;
    o.x = f2bf(v.x); o.y = f2bf(v.y); o.z = f2bf(v.z); o.w = f2bf(v.w);
    d[off] = o;
}

// ---------- QKV projection: 256x128 tile, 512 threads (8 waves, 4m x 2n) ----------
// R12's 2D XCD swizzle kept (each XCD: 4 m-tiles x 24 n-tiles; W-tile shared
// by 4 co-resident m-blocks in one L2 window).
// R13: single-barrier prefetch K-loop (attn's proven structure). The old
// {sync; GL16; sync; compute} drained vmcnt(0) on loads issued immediately
// before -> full L2/HBM latency exposed twice per K-step. Now: stage(ks+1)
// issues right after the barrier, compute(ks) covers its latency, ONE
// barrier per K-step (32 vs 64 drains/block). LDS double-buffered: 48 KB
// (2 x (As 16K + Bs 8K)); blocks/CU still 2 (VGPR-limited), unchanged.
__global__ __launch_bounds__(512, 4) void gemm_qkv_kernel(
    const bf16_t* __restrict__ A, const bf16_t* __restrict__ W,
    bf16_t* __restrict__ Qb, bf16_t* __restrict__ Kb, bf16_t* __restrict__ Vtb) {
    __shared__ bf16_t SMEM[24576];                 // 48 KB: buf b at b*12288 (As|Bs)
    const int tid = threadIdx.x;
    const int w = tid >> 6, lane = tid & 63;
    const int lrow = lane & 15, lq = lane >> 4;
    const int id_ = blockIdx.y * 24 + blockIdx.x;
    const int xcd_ = id_ & 7, r_ = id_ >> 3;
    const int bys = xcd_ * 4 + (r_ & 3), bxs = r_ >> 2;
    const int m0 = bys * 256, n0 = bxs * 128;
    const int srw = lane >> 2;                     // staging row-within-unit 0..15
    const int sk = (lane & 3) * 8;                 // staging k-chunk
    const int wm = (w & 3) * 64, wn = (w >> 2) * 64;
    v4f acc[4][4];
#pragma unroll
    for (int i = 0; i < 4; ++i)
#pragma unroll
        for (int j = 0; j < 4; ++j) acc[i][j] = (v4f){0.f, 0.f, 0.f, 0.f};

    // 24 wave-GL16 units (16 A + 8 B), 3 per wave; unit u stages 16 rows x 32 k
    auto stage = [&](int k0, int bb) {
        bf16_t* As_ = SMEM + bb * 12288;
        bf16_t* Bs_ = As_ + 8192;
#pragma unroll
        for (int c = 0; c < 3; ++c) {
            int u = w * 3 + c;
            if (u < 16)
                GL16(A + (size_t)(m0 + u * 16 + srw) * 1024 + k0 + sk, (char*)As_ + u * 1024);
            else
                GL16(W + (size_t)(n0 + (u - 16) * 16 + srw) * 1024 + k0 + sk,
                     (char*)Bs_ + (u - 16) * 1024);
        }
    };

    stage(0, 0);
    int buf = 0;
    for (int ks = 0; ks < 32; ++ks) {
        __syncthreads();                 // drains stage(ks) + all waves' LDS reads
        if (ks + 1 < 32) stage((ks + 1) * 32, buf ^ 1);
        const bf16_t* As = SMEM + buf * 12288;
        const bf16_t* Bs = As + 8192;
        bf16x8 af[4], bf[4];
#pragma unroll
        for (int i = 0; i < 4; ++i)
            af[i] = *(const bf16x8*)&As[(wm + i * 16 + lrow) * 32 + lq * 8];
#pragma unroll
        for (int j = 0; j < 4; ++j)
            bf[j] = *(const bf16x8*)&Bs[(wn + j * 16 + lrow) * 32 + lq * 8];
#pragma unroll
        for (int i = 0; i < 4; ++i)
#pragma unroll
            for (int j = 0; j < 4; ++j)
                acc[i][j] = __builtin_amdgcn_mfma_f32_16x16x32_bf16(af[i], bf[j],
                                                                    acc[i][j], 0, 0, 0);
        buf ^= 1;
    }

    const int x = bxs;                       // swizzled n-tile decides Q/K/V role
    const int b = m0 >> 12, t0 = m0 & 4095;  // 4096 % 256 == 0: tile never crosses batch
    if (x < 8) {
        // Q: (b,h,t,d), pre-scaled
#pragma unroll
        for (int i = 0; i < 4; ++i)
#pragma unroll
            for (int j = 0; j < 4; ++j)
#pragma unroll
                for (int r = 0; r < 4; ++r) {
                    int t = t0 + wm + i * 16 + lq * 4 + r;
                    int n = n0 + wn + j * 16 + lrow;
                    int h = n >> 6, d = n & 63;
                    Qb[(((size_t)b * 16 + h) * 4096 + t) * 64 + d] =
                        f2bf(acc[i][j][r] * QSCALE);
                }
    } else if (x < 16) {
        // K: (b,h,t,d)
#pragma unroll
        for (int i = 0; i < 4; ++i)
#pragma unroll
            for (int j = 0; j < 4; ++j)
#pragma unroll
                for (int r = 0; r < 4; ++r) {
                    int t = t0 + wm + i * 16 + lq * 4 + r;
                    int nn = n0 + wn + j * 16 + lrow - 1024;
                    int h = nn >> 6, d = nn & 63;
                    Kb[(((size_t)b * 16 + h) * 4096 + t) * 64 + d] = f2bf(acc[i][j][r]);
                }
    } else {
        // V: transpose through LDS (64 n-rows x 256 m per pass, 32 KB of SMEM),
        // xor-swizzled 8B granules; stores are 16B coalesced along t.
        const int d0 = n0 - 2048;
#pragma unroll 1
        for (int p = 0; p < 2; ++p) {
            __syncthreads();
            if ((w >> 2) == p) {             // the 4 waves holding n-half p
#pragma unroll
                for (int i = 0; i < 4; ++i)
#pragma unroll
                    for (int j = 0; j < 4; ++j) {
                        int row = j * 16 + lrow;            // n-local 0..63
                        int swz = (row & 7) << 1;
                        int g = (wm >> 2) + i * 4 + lq;     // m-granule 0..63
                        uint2 u;
                        u.x = (unsigned)f2bf(acc[i][j][0]) | ((unsigned)f2bf(acc[i][j][1]) << 16);
                        u.y = (unsigned)f2bf(acc[i][j][2]) | ((unsigned)f2bf(acc[i][j][3]) << 16);
                        *(uint2*)&SMEM[row * 256 + ((g ^ swz) << 2)] = u;
                    }
            }
            __syncthreads();
#pragma unroll
            for (int uu = 0; uu < 4; ++uu) {
                int unit = tid + 512 * uu;           // 2048 units = 64 rows x 32 segs
                int row = unit >> 5, seg = unit & 31;
                uint4 val = *(const uint4*)&SMEM[row * 256 + ((seg ^ (row & 7)) << 3)];
                *(uint4*)&Vtb[((size_t)b * 1024 + d0 + p * 64 + row) * 4096 + t0 + seg * 8] = val;
            }
        }
    }
}

// ---------- Output projection: out = Ob(8192x1024) @ Wo^T + bo, fp32 out ----------
// 128x128 tile, 4 waves, T1 XCD swizzle; R13 single-barrier prefetch loop
// (LDS double-buffered, 32 KB).
__global__ __launch_bounds__(256) void gemm_out_kernel(
    const bf16_t* __restrict__ A, const bf16_t* __restrict__ W,
    const float* __restrict__ bo, float* __restrict__ out) {
    __shared__ bf16_t SMEM[16384];                 // 32 KB: buf b at b*8192 (As|Bs)
    const int tid = threadIdx.x;
    const int w = tid >> 6, lane = tid & 63;
    const int lrow = lane & 15, lq = lane >> 4;
    const int nwg_ = gridDim.x * gridDim.y;
    const int id_ = blockIdx.y * gridDim.x + blockIdx.x;
    const int sid_ = (id_ & 7) * (nwg_ >> 3) + (id_ >> 3);
    const int bxs = sid_ % gridDim.x, bys = sid_ / gridDim.x;
    const int m0 = bys * 128, n0 = bxs * 128;
    const int srow = w * 16 + (lane >> 2);
    const int sk = (lane & 3) * 8;
    const int wm = (w & 1) * 64, wn = (w >> 1) * 64;
    v4f acc[4][4];
#pragma unroll
    for (int i = 0; i < 4; ++i)
#pragma unroll
        for (int j = 0; j < 4; ++j) acc[i][j] = (v4f){0.f, 0.f, 0.f, 0.f};

    auto stage = [&](int k0, int bb) {
        bf16_t* As_ = SMEM + bb * 8192;
        bf16_t* Bs_ = As_ + 4096;
        GL16(A + (size_t)(m0 + srow) * 1024 + k0 + sk,      (char*)As_ + w * 1024);
        GL16(A + (size_t)(m0 + 64 + srow) * 1024 + k0 + sk, (char*)As_ + 4096 + w * 1024);
        GL16(W + (size_t)(n0 + srow) * 1024 + k0 + sk,      (char*)Bs_ + w * 1024);
        GL16(W + (size_t)(n0 + 64 + srow) * 1024 + k0 + sk, (char*)Bs_ + 4096 + w * 1024);
    };

    stage(0, 0);
    int buf = 0;
    for (int ks = 0; ks < 32; ++ks) {
        __syncthreads();
        if (ks + 1 < 32) stage((ks + 1) * 32, buf ^ 1);
        const bf16_t* As = SMEM + buf * 8192;
        const bf16_t* Bs = As + 4096;
        bf16x8 af[4], bf[4];
#pragma unroll
        for (int i = 0; i < 4; ++i)
            af[i] = *(const bf16x8*)&As[(wm + i * 16 + lrow) * 32 + lq * 8];
#pragma unroll
        for (int j = 0; j < 4; ++j)
            bf[j] = *(const bf16x8*)&Bs[(wn + j * 16 + lrow) * 32 + lq * 8];
#pragma unroll
        for (int i = 0; i < 4; ++i)
#pragma unroll
            for (int j = 0; j < 4; ++j)
                acc[i][j] = __builtin_amdgcn_mfma_f32_16x16x32_bf16(af[i], bf[j],
                                                                    acc[i][j], 0, 0, 0);
        buf ^= 1;
    }

#pragma unroll
    for (int j = 0; j < 4; ++j) {
        int n = n0 + wn + j * 16 + lrow;
        float bias = bo[n];
#pragma unroll
        for (int i = 0; i < 4; ++i)
#pragma unroll
            for (int r = 0; r < 4; ++r) {
                int m = m0 + wm + i * 16 + lq * 4 + r;
                out[(size_t)m * 1024 + n] = acc[i][j][r] + bias;
            }
    }
}

// ---------- causal flash attention, v13 (FROZEN — structural floor) ----------
// v9 body + XCD-affine (g,bh) mapping (R9: FETCH 253->24.6 MB, dur 126.6->120.9).
// Occupancy (R2/R5/R6), pipelining (R1), setprio (R8) all measured-dead.
__global__ __launch_bounds__(256, 2) void attn_kernel(
    const bf16_t* __restrict__ Q, const bf16_t* __restrict__ K,
    const bf16_t* __restrict__ Vt, bf16_t* __restrict__ O) {
    __shared__ bf16_t Kls[2][64 * 64];   // [buf][t-row * 64d] swizzled, 8 KB/buf
    __shared__ bf16_t Vls[2][64 * 64];   // [buf][d-row * 64t] swizzled, 8 KB/buf
    const int tid = threadIdx.x;
    const int w = tid >> 6, lane = tid & 63;
    const int l31 = lane & 31, lh = lane >> 5;

    const int id = blockIdx.y * 16 + blockIdx.x;     // 0..511
    const int g = (id >> 3) & 15;                    // task-pair index 0..15
    const int bh = (id & 7) + ((id >> 7) << 3);      // XCD id%8 owns 4 bh

    const bf16_t* Qh = Q + (size_t)bh * (4096 * 64);
    const bf16_t* Kh = K + (size_t)bh * (4096 * 64);
    const bf16_t* Vh = Vt + (size_t)bh * (64 * 4096);
    const int b = bh >> 4, h = bh & 15;

    // staging: lane covers (row8 = lane>>3, slot = lane&7); slot s of row r
    // holds source granule s ^ (r&7); rows are 8 granules x 16B = 128 B
    const int svrow = lane >> 3;                 // row within 8-row GL16 block
    const int sg8 = ((lane & 7) ^ svrow) * 8;    // source granule elem offset
    const int rx = l31 & 7;                      // read-side row&7

    bf16x8 ones;
#pragma unroll
    for (int i = 0; i < 8; ++i) ones[i] = (__bf16)1.0f;

#pragma unroll 1
    for (int mem = 0; mem < 2; ++mem) {
        const int j = mem ? (31 - g) : g;   // 128-row task index (balanced pairs)
        const int q0 = j * 128;
        const int q0w = q0 + w * 32;        // this wave's 32 rows
        const int nt = 2 * j + 2;
        const int wlast = 2 * j + (w >> 1); // wave's diagonal tile
        const int qglob = q0w + l31;        // lane's q column

        bf16x8 qf[4];                       // B-operand: col q = l31, k = d
#pragma unroll
        for (int dk = 0; dk < 4; ++dk)
            qf[dk] = *(const bf16x8*)&Qh[(size_t)(q0w + l31) * 64 + dk * 16 + lh * 8];

        v16f oacc0 = zero16(), oacc1 = zero16(), lacc = zero16();

        // stage tile kt into buf: 16 GL16 (8 K + 8 V), 4 per wave
        auto stage = [&](int kt, int buf) {
            const int kc0 = kt << 6;
#pragma unroll
            for (int i = 0; i < 2; ++i) {
                int r0 = w * 16 + i * 8;
                GL16(Kh + (size_t)(kc0 + r0 + svrow) * 64 + sg8, (char*)&Kls[buf][r0 * 64]);
                GL16(Vh + (size_t)(r0 + svrow) * 4096 + kc0 + sg8, (char*)&Vls[buf][r0 * 64]);
            }
        };

        stage(0, 0);
        for (int kt = 0; kt < nt; ++kt) {
            const int buf = kt & 1;
            __syncthreads();                 // drains this wave's GL16s + all waves
            if (kt + 1 < nt) stage(kt + 1, buf ^ 1);
            if (kt > wlast) continue;        // fully-masked tile: loads+barriers only
            const int kc0 = kt << 6;
            const bool diag = (kt == wlast);

            // K fragments (A-operand: row t = th*32 + l31, k = d = dk*16+lh*8..)
            bf16x8 kf[2][4];
#pragma unroll
            for (int th = 0; th < 2; ++th)
#pragma unroll
                for (int dk = 0; dk < 4; ++dk)
                    kf[th][dk] = *(const bf16x8*)
                        &Kls[buf][(th * 32 + l31) * 64 + (((dk * 2 + lh) ^ rx) * 8)];
            // V fragments (B-operand: col d = db*32 + l31, k = t = kb*16+lh*8..)
            bf16x8 vf[2][4];
#pragma unroll
            for (int db = 0; db < 2; ++db)
#pragma unroll
                for (int kb = 0; kb < 4; ++kb)
                    vf[db][kb] = *(const bf16x8*)
                        &Vls[buf][(db * 32 + l31) * 64 + (((kb * 2 + lh) ^ rx) * 8)];

            // S^T = K Q^T, both t-halves interleaved (ILP 2)
            v16f st0 = zero16(), st1 = zero16();
#pragma unroll
            for (int dk = 0; dk < 4; ++dk) {
                st0 = __builtin_amdgcn_mfma_f32_32x32x16_bf16(kf[0][dk], qf[dk], st0, 0, 0, 0);
                st1 = __builtin_amdgcn_mfma_f32_32x32x16_bf16(kf[1][dk], qf[dk], st1, 0, 0, 0);
            }

            // P = 2^S (mask after exp on diag), packed to PV A-frags in-register.
            // Reg r of S^T holds t = th*32 + (r&3) + 8*(r>>2) + 4*lh.
            // A-frag kb needs t = kb*16 + lh*8 + j (j=0..7):
            //   dw0 = {base+8lh+0,1} dw1 = {+2,+3} dw2 = {+4,+5} dw3 = {+6,+7}.
            // x0/x1 = own low quad pairs, y0/y1 = own +8 quad pairs;
            // swap(x, y): ret.x = dw0/1 (lh0: own x; lh1: partner y),
            //             ret.y = dw2/3 (lh0: partner x; lh1: own y).
            bf16x8 pa[4];
#pragma unroll
            for (int th = 0; th < 2; ++th) {
                float p[16];
#pragma unroll
                for (int rr = 0; rr < 16; ++rr) {
                    float pv = __builtin_amdgcn_exp2f(th ? st1[rr] : st0[rr]);
                    if (diag) {
                        int tg = kc0 + th * 32 + (rr & 3) + 8 * (rr >> 2) + 4 * lh;
                        pv = (tg > qglob) ? 0.f : pv;
                    }
                    p[rr] = pv;
                }
#pragma unroll
                for (int kb2 = 0; kb2 < 2; ++kb2) {
                    unsigned x0 = cvtpk(p[kb2 * 8 + 0], p[kb2 * 8 + 1]);
                    unsigned x1 = cvtpk(p[kb2 * 8 + 2], p[kb2 * 8 + 3]);
                    unsigned y0 = cvtpk(p[kb2 * 8 + 4], p[kb2 * 8 + 5]);
                    unsigned y1 = cvtpk(p[kb2 * 8 + 6], p[kb2 * 8 + 7]);
                    u32x2 ra = __builtin_amdgcn_permlane32_swap(x0, y0, false, false);
                    u32x2 rb = __builtin_amdgcn_permlane32_swap(x1, y1, false, false);
                    union { unsigned u[4]; bf16x8 v; } pu;
                    pu.u[0] = ra.x; pu.u[1] = rb.x;   // t{base+8lh+0..3}
                    pu.u[2] = ra.y; pu.u[3] = rb.y;   // t{base+8lh+4..7}
                    pa[th * 2 + kb2] = pu.v;
                }
            }

            // l += P @ 1 ; O += P @ V
#pragma unroll
            for (int kb = 0; kb < 4; ++kb) {
                lacc  = __builtin_amdgcn_mfma_f32_32x32x16_bf16(pa[kb], ones,       lacc,  0, 0, 0);
                oacc0 = __builtin_amdgcn_mfma_f32_32x32x16_bf16(pa[kb], vf[0][kb], oacc0, 0, 0, 0);
                oacc1 = __builtin_amdgcn_mfma_f32_32x32x16_bf16(pa[kb], vf[1][kb], oacc1, 0, 0, 0);
            }
        }

        // epilogue: O = oacc / l  (lacc rows == oacc rows; any col holds the sum)
#pragma unroll
        for (int rr = 0; rr < 16; ++rr) {
            float rl = 1.0f / lacc[rr];
            int q = q0w + (rr & 3) + 8 * (rr >> 2) + 4 * lh;
            size_t o0 = ((size_t)b * 4096 + q) * 1024 + h * 64;
            O[o0 + l31]      = f2bf(oacc0[rr] * rl);
            O[o0 + 32 + l31] = f2bf(oacc1[rr] * rl);
        }
    }
}

// ---------- launch ----------
extern "C" void kernel_launch(void* const* d_in, const int* in_sizes, int n_in,
                              void* d_out, int out_size, void* d_ws, size_t ws_size,
                              hipStream_t stream) {
    const float* x  = (const float*)d_in[0];
    const float* Wq = (const float*)d_in[1];
    const float* Wk = (const float*)d_in[2];
    const float* Wv = (const float*)d_in[3];
    const float* Wo = (const float*)d_in[4];
    const float* bo = (const float*)d_in[5];
    float* out = (float*)d_out;

    char* ws = (char*)d_ws;
    bf16_t* xb   = (bf16_t*)(ws + 0);           // 8192x1024      16.78 MB
    bf16_t* Wqkv = (bf16_t*)(ws + 16777216);    // 3072x1024       6.29 MB
    bf16_t* Wob  = (bf16_t*)(ws + 23068672);    // 1024x1024       2.10 MB
    bf16_t* Qb   = (bf16_t*)(ws + 25165824);    // (b,h,t,d)      16.78 MB
    bf16_t* Kb   = (bf16_t*)(ws + 41943040);    // (b,h,t,d)      16.78 MB
    bf16_t* Vtb  = (bf16_t*)(ws + 58720256);    // (b,h,d,t)      16.78 MB
    bf16_t* Ob   = (bf16_t*)(ws + 75497472);    // 8192x1024      16.78 MB

    // fused converts (x, Wq, Wk, Wv, Wo) in one launch
    cvt_all<<<12288, 256, 0, stream>>>((const float4*)x, (const float4*)Wq,
                                       (const float4*)Wk, (const float4*)Wv,
                                       (const float4*)Wo,
                                       (ushort4*)xb, (ushort4*)Wqkv, (ushort4*)Wob);

    // QKV projection (M=8192, N=3072): 256x128 tiles, 512 threads, 2D XCD
    // swizzle, single-barrier prefetch loop
    gemm_qkv_kernel<<<dim3(24, 32), 512, 0, stream>>>(xb, Wqkv, Qb, Kb, Vtb);

    // causal flash attention (v13, frozen)
    attn_kernel<<<dim3(16, 32), 256, 0, stream>>>(Qb, Kb, Vtb, Ob);

    // output projection (M=8192, N=1024) + bias, single-barrier prefetch loop
    gemm_out_kernel<<<dim3(8, 64), 256, 0, stream>>>(Ob, Wob, bo, out);
}